// Round 4
// baseline (2381.776 us; speedup 1.0000x reference)
//
#include <hip/hip_runtime.h>

typedef unsigned short u16;
typedef __attribute__((ext_vector_type(8))) short frag8;
typedef __attribute__((ext_vector_type(4))) float f32x4;
typedef __attribute__((ext_vector_type(8))) unsigned short u16x8;

// address-space typedefs for global_load_lds
typedef __attribute__((address_space(1))) const void GV;
typedef __attribute__((address_space(3))) void LV;

__device__ __forceinline__ void gl16(const u16* g, u16* l) {
  // async global->LDS, 16B per lane; LDS dest = wave-uniform base + lane*16
  __builtin_amdgcn_global_load_lds((GV*)g, (LV*)l, 16, 0, 0);
}

__device__ __forceinline__ float b2f(u16 u) {
  union { unsigned int i; float f; } v; v.i = ((unsigned int)u) << 16; return v.f;
}
__device__ __forceinline__ u16 f2b(float f) {
  union { float f; unsigned int i; } v; v.f = f;
  unsigned int x = v.i;
  x += 0x7fffu + ((x >> 16) & 1u);
  return (u16)(x >> 16);
}
// fast tanh: 1 - 2/(e^{2x}+1). Large +x: e=inf -> 1; large -x: e=0 -> -1.
// |err| ~1e-6 relative, dwarfed by bf16 rounding (~3e-3) in this pipeline.
__device__ __forceinline__ float ftanh(float x) {
  float e = __expf(2.f * x);
  return 1.f - 2.f / (e + 1.f);
}

// ---------------------------------------------------------------------------
// Prep kernels — f32 inputs; everything GEMM-facing becomes bf16 once here.
// ---------------------------------------------------------------------------
__global__ void cvt3(const float* __restrict__ s0, const float* __restrict__ s1,
                     const float* __restrict__ s2, u16* __restrict__ d0,
                     u16* __restrict__ d1, u16* __restrict__ d2) {
  int i = blockIdx.x * 256 + threadIdx.x;   // 3 * 3145728
  int which = i / 3145728;
  int j = i - which * 3145728;
  const float* s = (which == 0) ? s0 : (which == 1 ? s1 : s2);
  u16* d = (which == 0) ? d0 : (which == 1 ? d1 : d2);
  d[j] = f2b(s[j]);
}

__global__ void cvt2(const float* __restrict__ s0, const float* __restrict__ s1,
                     u16* __restrict__ d0, u16* __restrict__ d1) {
  int i = blockIdx.x * 256 + threadIdx.x;   // 2 * 1048576
  if (i < 1048576) d0[i] = f2b(s0[i]);
  else             d1[i - 1048576] = f2b(s1[i - 1048576]);
}

// Split g1_wih [3072, 642] (f32) into bf16 Wc [3072,512] and Wd [3072,192]
// (zero-padded cols 130..191 so K is a multiple of BK=32 twice over).
__global__ void prep_w1(const float* __restrict__ wih, u16* __restrict__ Wc, u16* __restrict__ Wd) {
  int i = blockIdx.x * 256 + threadIdx.x;
  const int NC = 3072 * 512;
  const int ND = 3072 * 192;
  if (i < NC) {
    int n = i >> 9, k = i & 511;
    Wc[i] = f2b(wih[n * 642 + k]);
  } else if (i < NC + ND) {
    int j = i - NC;
    int n = j / 192, k = j - n * 192;
    Wd[j] = (k < 130) ? f2b(wih[n * 642 + 512 + k]) : (u16)0;
  }
}

// fco_w [130,1024] f32 -> bf16 WBy [256,1024], zero rows 130..255
__global__ void prep_wby(const float* __restrict__ fcow, u16* __restrict__ wby) {
  int i = blockIdx.x * 256 + threadIdx.x;   // 256*1024
  int n = i >> 10;
  wby[i] = (n < 130) ? f2b(fcow[i]) : (u16)0;
}

// prev matrix P[32768][192] bf16: row = t*2048 + e*128 + b, tt = e*16+t;
// P[row][k] = (tt>0 && k<130) ? target[b][tt-1][k] : 0. Replaces the r9 UDA
// gather-GEMM: one cheap pass (17MB rd / 12.6MB wr ~ 5us) makes gi1_all a
// plain pipelined GEMM.
__global__ void prep_prev(const float* __restrict__ target, u16* __restrict__ P) {
  int i = blockIdx.x * 256 + threadIdx.x;   // 32768 * 24 chunks of 8
  int row = i / 24;
  int c8  = i - row * 24;
  int k0 = c8 * 8;
  int t = row >> 11, m2 = row & 2047;
  int e = m2 >> 7, b = m2 & 127;
  int tt = e * 16 + t;
  u16x8 r;
  if (tt > 0 && k0 + 8 <= 130) {
    const float* trow = target + (size_t)(b * 256 + tt - 1) * 130 + k0;
#pragma unroll
    for (int q = 0; q < 8; ++q) r[q] = f2b(trow[q]);
  } else if (tt > 0 && k0 < 130) {
    const float* trow = target + (size_t)(b * 256 + tt - 1) * 130;
#pragma unroll
    for (int q = 0; q < 8; ++q) { int k = k0 + q; r[q] = (k < 130) ? f2b(trow[k]) : (u16)0; }
  } else {
#pragma unroll
    for (int q = 0; q < 8; ++q) r[q] = (u16)0;
  }
  *(u16x8*)&P[(size_t)row * 192 + k0] = r;
}

// ---------------------------------------------------------------------------
// GEMM core. 128x128 tile, BK=32, **256 threads = 4 waves**, wave tile 64x64
// as 4x4 acc of mfma 16x16x32 bf16 (m97-verified geometry), f32 accum.
//
// r10 rationale: r9 (8 waves x 2x4 acc) measured 3250 cyc/K-step-round vs
// floors MFMA 930 / LDS 1285 -> issue/sync-bound: 24 waves/CU, only 8 MFMA
// between barriers, 768 B LDS per MFMA. Now: 8 ds_read_b128 -> 16 MFMA
// (512 B/MFMA, 1.5x less LDS), half the waves per barrier, 2x work per wave.
//
// K-loop: 3-buffer counted-vmcnt (T4). Prologue issues tiles 0,1 (8 gl16);
// iter ks: s_waitcnt vmcnt(4) [tile ks landed; every wave waits its OWN
// loads, so post-barrier ALL slabs are valid] -> s_barrier -> issue tile
// ks+2 (4 gl16) -> 8 ds_read + 16 MFMA on buf ks%3. Buf (ks+2)%3 was last
// read in iter ks-1; the iter-ks barrier orders those reads before the new
// gl16 lands. Last iter waits vmcnt(0).
//
// Swizzle (rule 21, both sides): LDS image [row][c] holds global chunk
// c ^ ((row>>1)&3). Staging: source col pre-swizzled, gl16 dest linear;
// wave w stages rows [w*32,w*32+32) via 2 gl16 per matrix (rows +0,+16;
// (row>>1)&3 invariant under +16/+32/+64 offsets). Reads: chunk (lq^sw),
// sw=(lr>>1)&3 -> quad (4r+chunk') mod 8 bijective per 8-lane group
// (measured 0 conflicts in r9).
// ---------------------------------------------------------------------------
__device__ __forceinline__ void kloop3(
    const u16* gA, int lda, const u16* gB, int ldb, int nk,
    u16* AsBase, u16* BsBase, int wave,
    int rdA, int rdB, f32x4 (&acc)[4][4])
{
  u16* Ad = AsBase + wave * 1024;   // wave slab: 32 rows x 32 u16
  u16* Bd = BsBase + wave * 1024;
  const u16* gA2 = gA + 16 * lda;
  const u16* gB2 = gB + 16 * ldb;
  // prologue: tiles 0,1 in flight (nk >= 2 always here)
  gl16(gA,      Ad);        gl16(gA2,      Ad + 512);
  gl16(gB,      Bd);        gl16(gB2,      Bd + 512);
  gl16(gA + 32, Ad + 4096); gl16(gA2 + 32, Ad + 4096 + 512);
  gl16(gB + 32, Bd + 4096); gl16(gB2 + 32, Bd + 4096 + 512);
  int cbuf = 0, nbuf = 2;
  int koff = 64;
  for (int ks = 0; ks < nk; ++ks) {
    if (ks < nk - 1) asm volatile("s_waitcnt vmcnt(4)" : : : "memory");
    else             asm volatile("s_waitcnt vmcnt(0)" : : : "memory");
    __builtin_amdgcn_s_barrier();
    __builtin_amdgcn_sched_barrier(0);
    if (ks + 2 < nk) {
      gl16(gA + koff,  Ad + nbuf * 4096);       gl16(gA2 + koff, Ad + nbuf * 4096 + 512);
      gl16(gB + koff,  Bd + nbuf * 4096);       gl16(gB2 + koff, Bd + nbuf * 4096 + 512);
      koff += 32;
    }
    const u16* Ab = AsBase + cbuf * 4096;
    const u16* Bb = BsBase + cbuf * 4096;
    frag8 af[4], bfr[4];
#pragma unroll
    for (int i = 0; i < 4; ++i)
      af[i] = *(const frag8*)&Ab[rdA + i * 512];
#pragma unroll
    for (int j = 0; j < 4; ++j)
      bfr[j] = *(const frag8*)&Bb[rdB + j * 512];
#pragma unroll
    for (int i = 0; i < 4; ++i)
#pragma unroll
      for (int j = 0; j < 4; ++j)
        acc[i][j] = __builtin_amdgcn_mfma_f32_16x16x32_bf16(af[i], bfr[j], acc[i][j], 0, 0, 0);
    cbuf = (cbuf == 2) ? 0 : cbuf + 1;
    nbuf = (nbuf == 2) ? 0 : nbuf + 1;
  }
}

// ---------------------------------------------------------------------------
// bt-GEMM: C[m][n] = sum_k A[m][k]*Bsel[n'][k].  A,B bf16.
//   Bsel/n' per 128-tile: n0<n_split -> B0,n'=n else B1,n'=n-n_split
// Epilogue modes:
//  0: out0(bf16)[m*N+n] = acc + bias0[n]
//  1: t=tanh(acc+bias0[n]); n<1024 -> h1 else h2; write f32 (fout*) AND bf16 (out*)
//  2: out0(bf16)[m*N+n] = acc + b2f(addmat[(m&2047)*3072+n])          [N=3072]
//  3: n<3072 -> out0+bias0 (gi2) ; else out1+bias1 (gh1)              [N=6144]
//  4: n<3072 -> out0+bias0 (gh2) ; 3072<=n<3202 -> y(f32) scatter     [N=3328]
// ---------------------------------------------------------------------------
__global__ __launch_bounds__(256, 3) void gemm_bt(
    const u16* __restrict__ A, int lda,
    const u16* __restrict__ B0, const u16* __restrict__ B1, int ldb, int n_split,
    int N, int K, int mode, int tstep,
    const float* __restrict__ bias0, const float* __restrict__ bias1,
    u16* __restrict__ out0, u16* __restrict__ out1,
    const u16* __restrict__ addmat,
    float* __restrict__ fout0, float* __restrict__ fout1)
{
  __shared__ u16 As[3 * 4096];
  __shared__ u16 Bs[3 * 4096];

  const int tid = threadIdx.x;
  const int wave = tid >> 6;
  const int lane = tid & 63;
  const int m0 = blockIdx.y * 128;
  const int n0 = blockIdx.x * 128;
  const int wm = (wave & 1) * 64;    // wave m-offset (2 waves down)
  const int wn = (wave >> 1) * 64;   // wave n-offset (2 waves across)
  const int lr = lane & 15;
  const int lq = lane >> 4;
  const int sw = (lr >> 1) & 3;                  // read-side swizzle
  const int rdA = (wm + lr) * 32 + ((lq ^ sw) << 3);
  const int rdB = (wn + lr) * 32 + ((lq ^ sw) << 3);

  const u16* Bsel;
  int nb0;
  if (n0 < n_split) { Bsel = B0; nb0 = n0; }
  else              { Bsel = B1; nb0 = n0 - n_split; }

  f32x4 acc[4][4] = {};

  // staging source coords: wave slab rows w*32+(lane>>2) (+16 in kloop3),
  // chunk pre-swizzled: (lane&3) ^ ((lane>>3)&3) == chunk ^ ((row>>1)&3).
  const int srow_g = wave * 32 + (lane >> 2);
  const int scol_g = (((lane & 3) ^ ((lane >> 3) & 3)) << 3);
  const u16* gA = &A[(size_t)(m0 + srow_g) * lda + scol_g];
  const u16* gB = &Bsel[(size_t)(nb0 + srow_g) * ldb + scol_g];

  kloop3(gA, lda, gB, ldb, K >> 5, As, Bs, wave, rdA, rdB, acc);

  // C/D layout: col = lane&15 (n), row = (lane>>4)*4 + reg (m).
#pragma unroll
  for (int i = 0; i < 4; ++i) {
#pragma unroll
    for (int r = 0; r < 4; ++r) {
      int m = m0 + wm + i * 16 + lq * 4 + r;
#pragma unroll
      for (int j = 0; j < 4; ++j) {
        int n = n0 + wn + j * 16 + lr;
        float v = acc[i][j][r];
        if (mode == 0) {
          out0[(size_t)m * N + n] = f2b(v + bias0[n]);
        } else if (mode == 1) {
          float t = ftanh(v + bias0[n]);
          if (n < 1024) { fout0[(size_t)m * 1024 + n] = t;          out0[(size_t)m * 1024 + n] = f2b(t); }
          else          { fout1[(size_t)m * 1024 + (n - 1024)] = t; out1[(size_t)m * 1024 + (n - 1024)] = f2b(t); }
        } else if (mode == 2) {
          out0[(size_t)m * N + n] = f2b(v + b2f(addmat[(size_t)(m & 2047) * 3072 + n]));
        } else if (mode == 3) {
          if (n < 3072) out0[(size_t)m * 3072 + n] = f2b(v + bias0[n]);
          else          out1[(size_t)m * 3072 + (n - 3072)] = f2b(v + bias1[n - 3072]);
        } else { // mode 4
          if (n < 3072) {
            out0[(size_t)m * 3072 + n] = f2b(v + bias0[n]);
          } else if (n < 3202) {
            int d = n - 3072;
            int b = m & 127, e = m >> 7;
            fout0[(size_t)((b << 8) + (e << 4) + tstep) * 130 + d] = v + bias1[d];
          }
        }
      }
    }
  }
}

// ---------------------------------------------------------------------------
// Fused step GEMM: gemm3(t) [gi2 = h1@W2i ; gh1' = h1@W1h] and gemm4(t-1)
// [gh2' = h2@W2h ; y = h2@WBy] in ONE dispatch. N = 9472 -> 74 x 16 = 1184
// blocks. Regions by n0: [0,3072) gi2 | [3072,6144) gh1 | [6144,9216) gh2 |
// [9216,9472) y (WBy zero-padded to 256 rows, scatter cols <130).
// K = 1024, lda = ldb = 1024 for all regions.
// ---------------------------------------------------------------------------
__global__ __launch_bounds__(256, 3) void gemm_fused(
    const u16* __restrict__ A1, const u16* __restrict__ A2,
    const u16* __restrict__ W2i, const u16* __restrict__ W1h,
    const u16* __restrict__ W2h, const u16* __restrict__ WBy,
    const float* __restrict__ b_gi2, const float* __restrict__ b_gh1,
    const float* __restrict__ b_gh2, const float* __restrict__ b_y,
    u16* __restrict__ gi2, u16* __restrict__ gh1, u16* __restrict__ gh2,
    float* __restrict__ y, int tstep)
{
  __shared__ u16 As[3 * 4096];
  __shared__ u16 Bs[3 * 4096];

  const int tid = threadIdx.x;
  const int wave = tid >> 6;
  const int lane = tid & 63;
  const int m0 = blockIdx.y * 128;
  const int n0 = blockIdx.x * 128;
  const int wm = (wave & 1) * 64;
  const int wn = (wave >> 1) * 64;
  const int lr = lane & 15;
  const int lq = lane >> 4;
  const int sw = (lr >> 1) & 3;
  const int rdA = (wm + lr) * 32 + ((lq ^ sw) << 3);
  const int rdB = (wn + lr) * 32 + ((lq ^ sw) << 3);

  const int reg = (n0 >= 9216) ? 3 : (n0 / 3072);
  const int nb0 = n0 - reg * 3072;
  const u16* A  = (reg < 2) ? A1 : A2;
  const u16* Bw = (reg == 0) ? W2i : (reg == 1) ? W1h : (reg == 2) ? W2h : WBy;
  const float* bias = (reg == 0) ? b_gi2 : (reg == 1) ? b_gh1 : (reg == 2) ? b_gh2 : b_y;

  const int srow_g = wave * 32 + (lane >> 2);
  const int scol_g = (((lane & 3) ^ ((lane >> 3) & 3)) << 3);
  const u16* gA = &A[(size_t)(m0 + srow_g) * 1024 + scol_g];
  const u16* gB = &Bw[(size_t)(nb0 + srow_g) * 1024 + scol_g];

  f32x4 acc[4][4] = {};
  kloop3(gA, 1024, gB, 1024, 32, As, Bs, wave, rdA, rdB, acc);

#pragma unroll
  for (int i = 0; i < 4; ++i) {
#pragma unroll
    for (int r = 0; r < 4; ++r) {
      int m = m0 + wm + i * 16 + lq * 4 + r;
#pragma unroll
      for (int j = 0; j < 4; ++j) {
        int nl = nb0 + wn + j * 16 + lr;
        float v = acc[i][j][r];
        if (reg == 0)      gi2[(size_t)m * 3072 + nl] = f2b(v + bias[nl]);
        else if (reg == 1) gh1[(size_t)m * 3072 + nl] = f2b(v + bias[nl]);
        else if (reg == 2) gh2[(size_t)m * 3072 + nl] = f2b(v + bias[nl]);
        else if (nl < 130) {
          int b = m & 127, e = m >> 7;
          y[(size_t)((b << 8) + (e << 4) + tstep) * 130 + nl] = v + bias[nl];
        }
      }
    }
  }
}

// ---------------------------------------------------------------------------
// Fused GRU combine: slot A = combine1(t) [h1 <- GRU1], slot B =
// combine2(t-1) [h2 <- GRU2]. h = (1-z)*n + z*h; gi/gh bf16 [2048,3072]
// (biases folded), h32 f32 master state (in place), hb16 bf16 shadow.
// ---------------------------------------------------------------------------
__global__ __launch_bounds__(256) void gru2(
    const u16* __restrict__ giA, const u16* __restrict__ ghA,
    float* __restrict__ hA, u16* __restrict__ hbA,
    const u16* __restrict__ giB, const u16* __restrict__ ghB,
    float* __restrict__ hB, u16* __restrict__ hbB,
    int doA, int doB)
{
  int blk = blockIdx.x;
  const u16 *gi, *gh; float* h32; u16* hb16;
  if (blk < 1024) { if (!doA) return; gi = giA; gh = ghA; h32 = hA; hb16 = hbA; }
  else { if (!doB) return; gi = giB; gh = ghB; h32 = hB; hb16 = hbB; blk -= 1024; }
  int idx = blk * 256 + threadIdx.x;   // 0 .. 2048*128-1
  int m = idx >> 7;
  int j0 = (idx & 127) << 3;
  const size_t gb = (size_t)m * 3072 + j0;
  const size_t hb = (size_t)m * 1024 + j0;
  u16x8 ir = *(const u16x8*)&gi[gb];
  u16x8 iz = *(const u16x8*)&gi[gb + 1024];
  u16x8 in_ = *(const u16x8*)&gi[gb + 2048];
  u16x8 hr = *(const u16x8*)&gh[gb];
  u16x8 hz = *(const u16x8*)&gh[gb + 1024];
  u16x8 hn = *(const u16x8*)&gh[gb + 2048];
  f32x4 h0 = *(const f32x4*)&h32[hb];
  f32x4 h1v = *(const f32x4*)&h32[hb + 4];
  f32x4 o0, o1;
  u16x8 ob;
#pragma unroll
  for (int q = 0; q < 8; ++q) {
    float r = 1.f / (1.f + __expf(-(b2f(ir[q]) + b2f(hr[q]))));
    float z = 1.f / (1.f + __expf(-(b2f(iz[q]) + b2f(hz[q]))));
    float nn = ftanh(b2f(in_[q]) + r * b2f(hn[q]));
    float hh = (q < 4) ? h0[q & 3] : h1v[q & 3];
    float res = (1.f - z) * nn + z * hh;
    if (q < 4) o0[q & 3] = res; else o1[q & 3] = res;
    ob[q] = f2b(res);
  }
  *(f32x4*)&h32[hb] = o0;
  *(f32x4*)&h32[hb + 4] = o1;
  *(u16x8*)&hb16[hb] = ob;
}

// ---------------------------------------------------------------------------
extern "C" void kernel_launch(void* const* d_in, const int* in_sizes, int n_in,
                              void* d_out, int out_size, void* d_ws, size_t ws_size,
                              hipStream_t stream)
{
  const float* c      = (const float*)d_in[0];
  const float* target = (const float*)d_in[1];
  const float* fiw    = (const float*)d_in[4];
  const float* fib    = (const float*)d_in[5];
  const float* g1wih  = (const float*)d_in[6];
  const float* g1whh  = (const float*)d_in[7];
  const float* g1bih  = (const float*)d_in[8];
  const float* g1bhh  = (const float*)d_in[9];
  const float* g2wih  = (const float*)d_in[10];
  const float* g2whh  = (const float*)d_in[11];
  const float* g2bih  = (const float*)d_in[12];
  const float* g2bhh  = (const float*)d_in[13];
  const float* fcow   = (const float*)d_in[14];
  const float* fcob   = (const float*)d_in[15];
  float* out = (float*)d_out;

  char* wsp = (char*)d_ws;
  size_t off = 0;
  auto takeb = [&](size_t bytes) {
    void* p = (void*)(wsp + off);
    off += bytes;
    off = (off + 255) & ~(size_t)255;
    return p;
  };
  float* h1f = (float*)takeb((size_t)2048 * 1024 * 4);
  float* h2f = (float*)takeb((size_t)2048 * 1024 * 4);
  u16* h1b   = (u16*)takeb((size_t)2048 * 1024 * 2);
  u16* h2b   = (u16*)takeb((size_t)2048 * 1024 * 2);
  u16* gic   = (u16*)takeb((size_t)2048 * 3072 * 2);
  u16* gib   = (u16*)takeb((size_t)2048 * 3072 * 2);
  u16* gh1   = (u16*)takeb((size_t)2048 * 3072 * 2);
  u16* gh2   = (u16*)takeb((size_t)2048 * 3072 * 2);
  u16* cbf   = (u16*)takeb((size_t)2048 * 512 * 2);
  u16* Wfi   = (u16*)takeb((size_t)2048 * 512 * 2);
  u16* Wc    = (u16*)takeb((size_t)3072 * 512 * 2);
  u16* Wd    = (u16*)takeb((size_t)3072 * 192 * 2);
  u16* W1h   = (u16*)takeb((size_t)3072 * 1024 * 2);
  u16* W2i   = (u16*)takeb((size_t)3072 * 1024 * 2);
  u16* W2h   = (u16*)takeb((size_t)3072 * 1024 * 2);
  u16* WBy   = (u16*)takeb((size_t)256 * 1024 * 2);
  u16* P     = (u16*)takeb((size_t)32768 * 192 * 2);   // prev matrix, all t
  // base ~112 MiB. gi1_all (all 16 timesteps of gi1, teacher-forced so
  // h-independent) costs +192 MiB — take it only if ws allows.
  const size_t GI1_BYTES = (size_t)16 * 2048 * 3072 * 2;
  u16* gi1 = nullptr;
  if (ws_size >= off + GI1_BYTES + 256) gi1 = (u16*)takeb(GI1_BYTES);
  (void)in_sizes; (void)n_in; (void)out_size;

  const int BIG = 1 << 30;   // n_split sentinel: always B0

  // --- one-time prep: conversions to bf16 ---
  cvt2<<<8192, 256, 0, stream>>>(c, fiw, cbf, Wfi);
  cvt3<<<36864, 256, 0, stream>>>(g1whh, g2wih, g2whh, W1h, W2i, W2h);
  prep_w1 <<<8448, 256, 0, stream>>>(g1wih, Wc, Wd);
  prep_wby<<<1024, 256, 0, stream>>>(fcow, WBy);
  prep_prev<<<3072, 256, 0, stream>>>(target, P);

  // --- init ---
  // h1,h2 = tanh(c @ fiw.T + fib)  (f32 + bf16 shadow)
  gemm_bt<<<dim3(16, 16), 256, 0, stream>>>(cbf, 512, Wfi, nullptr, 512, BIG,
                                            2048, 512, 1, 0, fib, nullptr,
                                            h1b, h2b, nullptr, h1f, h2f);
  // gi_c = c @ Wc.T + g1bih
  gemm_bt<<<dim3(24, 16), 256, 0, stream>>>(cbf, 512, Wc, nullptr, 512, BIG,
                                            3072, 512, 0, 0, g1bih, nullptr,
                                            gic, nullptr, nullptr, nullptr, nullptr);
  // gh1 = h1 @ g1whh.T + g1bhh
  gemm_bt<<<dim3(24, 16), 256, 0, stream>>>(h1b, 1024, W1h, nullptr, 1024, BIG,
                                            3072, 1024, 0, 0, g1bhh, nullptr,
                                            gh1, nullptr, nullptr, nullptr, nullptr);
  // gh2 = h2 @ g2whh.T + g2bhh
  gemm_bt<<<dim3(24, 16), 256, 0, stream>>>(h2b, 1024, W2h, nullptr, 1024, BIG,
                                            3072, 1024, 0, 0, g2bhh, nullptr,
                                            gh2, nullptr, nullptr, nullptr, nullptr);

  if (gi1 != nullptr) {
    // gi1 for ALL t in one GEMM (M=32768): gi1_all = P @ Wd.T + gic (row-broadcast)
    gemm_bt<<<dim3(24, 256), 256, 0, stream>>>(P, 192, Wd, nullptr, 192, BIG,
                                               3072, 192, 2, 0, nullptr, nullptr,
                                               gi1, nullptr, gic, nullptr, nullptr);

    // --- recurrence: alternating C(t) -> G(t), 2 dispatches per step ---
    gru2<<<2048, 256, 0, stream>>>(gi1, gh1, h1f, h1b, nullptr, nullptr, nullptr, nullptr, 1, 0);
    gemm_bt<<<dim3(48, 16), 256, 0, stream>>>(h1b, 1024, W2i, W1h, 1024, 3072,
                                              6144, 1024, 3, 0, g2bih, g1bhh,
                                              gib, gh1, nullptr, nullptr, nullptr);
    for (int t = 1; t < 16; ++t) {
      // C(t): combine1(t) [gi1_t, gh1] + combine2(t-1) [gi2, gh2]
      gru2<<<2048, 256, 0, stream>>>(gi1 + (size_t)t * 2048 * 3072, gh1, h1f, h1b,
                                     gib, gh2, h2f, h2b, 1, 1);
      // G(t): gemm3(t) + gemm4(t-1); y uses tstep = t-1
      gemm_fused<<<dim3(74, 16), 256, 0, stream>>>(h1b, h2b, W2i, W1h, W2h, WBy,
                                                   g2bih, g1bhh, g2bhh, fcob,
                                                   gib, gh1, gh2, out, t - 1);
    }
    // C(16): combine2(15) only
    gru2<<<2048, 256, 0, stream>>>(nullptr, nullptr, nullptr, nullptr,
                                   gib, gh2, h2f, h2b, 0, 1);
    // G(16): gemm4(15): gh2' (discarded) + y(15)
    gemm_bt<<<dim3(26, 16), 256, 0, stream>>>(h2b, 1024, W2h, WBy, 1024, 3072,
                                              3328, 1024, 4, 15, g2bhh, fcob,
                                              gh2, nullptr, nullptr, out, nullptr);
  } else {
    // fallback (small ws): per-step sequence, gi1 from P slice
    for (int t = 0; t < 16; ++t) {
      gemm_bt<<<dim3(24, 16), 256, 0, stream>>>(P + (size_t)t * 2048 * 192, 192, Wd, nullptr, 192, BIG,
                                                3072, 192, 2, 0, nullptr, nullptr,
                                                gib, nullptr, gic, nullptr, nullptr);
      gru2<<<2048, 256, 0, stream>>>(gib, gh1, h1f, h1b, nullptr, nullptr, nullptr, nullptr, 1, 0);
      gemm_bt<<<dim3(48, 16), 256, 0, stream>>>(h1b, 1024, W2i, W1h, 1024, 3072,
                                                6144, 1024, 3, 0, g2bih, g1bhh,
                                                gib, gh1, nullptr, nullptr, nullptr);
      gru2<<<2048, 256, 0, stream>>>(gib, gh2, h2f, h2b, nullptr, nullptr, nullptr, nullptr, 1, 0);
      gemm_bt<<<dim3(26, 16), 256, 0, stream>>>(h2b, 1024, W2h, WBy, 1024, 3072,
                                                3328, 1024, 4, t, g2bhh, fcob,
                                                gh2, nullptr, nullptr, out, nullptr);
    }
  }
}

// Round 5
// 1891.708 us; speedup vs baseline: 1.2591x; 1.2591x over previous
//
#include <hip/hip_runtime.h>

typedef unsigned short u16;
typedef __attribute__((ext_vector_type(8))) short frag8;
typedef __attribute__((ext_vector_type(4))) float f32x4;
typedef __attribute__((ext_vector_type(8))) unsigned short u16x8;

// address-space typedefs for global_load_lds
typedef __attribute__((address_space(1))) const void GV;
typedef __attribute__((address_space(3))) void LV;

__device__ __forceinline__ void gl16(const u16* g, u16* l) {
  // async global->LDS, 16B per lane; LDS dest = wave-uniform base + lane*16
  __builtin_amdgcn_global_load_lds((GV*)g, (LV*)l, 16, 0, 0);
}

__device__ __forceinline__ float b2f(u16 u) {
  union { unsigned int i; float f; } v; v.i = ((unsigned int)u) << 16; return v.f;
}
__device__ __forceinline__ u16 f2b(float f) {
  union { float f; unsigned int i; } v; v.f = f;
  unsigned int x = v.i;
  x += 0x7fffu + ((x >> 16) & 1u);
  return (u16)(x >> 16);
}
// fast tanh: 1 - 2/(e^{2x}+1). Large +x: e=inf -> 1; large -x: e=0 -> -1.
__device__ __forceinline__ float ftanh(float x) {
  float e = __expf(2.f * x);
  return 1.f - 2.f / (e + 1.f);
}

// ---------------------------------------------------------------------------
// XCD-aware blockIdx remap (T1, m204 bijective form). HW assigns linear
// blockIdx round-robin to the 8 XCDs (bid%8). Remap so each XCD owns a
// CONTIGUOUS range of the partition axis:
//   axis 0: XCD owns an x-range (all y)  -> B-slice fits 4MB per-XCD L2.
//   axis 1: XCD owns a y-range (all x)  -> A-slice L2-resident (gi1_all).
// Pure bijection (q/r handles nwg%8!=0) — perf-only, cannot affect
// correctness. r11 rationale: staged bytes/dispatch (393MB at mode-3-class)
// over dur = 8.3 TB/s = L3 BW plateau; 64 FLOP/B * 8.3 = 531 TF = measured
// 533. B (12-19MB) misses per-XCD L2 by default; n-partition makes each
// XCD's B-slice ~2.4MB -> L2-resident -> halves L3 traffic.
// ---------------------------------------------------------------------------
__device__ __forceinline__ void xcd_remap(int axis, int& bx, int& by) {
  const int nx = gridDim.x, ny = gridDim.y;
  const int nwg = nx * ny;
  const int bid = blockIdx.x + nx * blockIdx.y;
  const int q = nwg >> 3, r = nwg & 7;
  const int xcd = bid & 7, i = bid >> 3;
  const int rem = (xcd < r ? xcd * (q + 1) : r * (q + 1) + (xcd - r) * q) + i;
  if (axis == 0) { bx = rem / ny; by = rem - bx * ny; }   // contiguous x per XCD
  else           { by = rem / nx; bx = rem - by * nx; }   // contiguous y per XCD
}

// ---------------------------------------------------------------------------
// Prep kernels — f32 inputs; everything GEMM-facing becomes bf16 once here.
// ---------------------------------------------------------------------------
__global__ void cvt3(const float* __restrict__ s0, const float* __restrict__ s1,
                     const float* __restrict__ s2, u16* __restrict__ d0,
                     u16* __restrict__ d1, u16* __restrict__ d2) {
  int i = blockIdx.x * 256 + threadIdx.x;   // 3 * 3145728
  int which = i / 3145728;
  int j = i - which * 3145728;
  const float* s = (which == 0) ? s0 : (which == 1 ? s1 : s2);
  u16* d = (which == 0) ? d0 : (which == 1 ? d1 : d2);
  d[j] = f2b(s[j]);
}

__global__ void cvt2(const float* __restrict__ s0, const float* __restrict__ s1,
                     u16* __restrict__ d0, u16* __restrict__ d1) {
  int i = blockIdx.x * 256 + threadIdx.x;   // 2 * 1048576
  if (i < 1048576) d0[i] = f2b(s0[i]);
  else             d1[i - 1048576] = f2b(s1[i - 1048576]);
}

// Split g1_wih [3072, 642] (f32) into bf16 Wc [3072,512] and Wd [3072,192]
__global__ void prep_w1(const float* __restrict__ wih, u16* __restrict__ Wc, u16* __restrict__ Wd) {
  int i = blockIdx.x * 256 + threadIdx.x;
  const int NC = 3072 * 512;
  const int ND = 3072 * 192;
  if (i < NC) {
    int n = i >> 9, k = i & 511;
    Wc[i] = f2b(wih[n * 642 + k]);
  } else if (i < NC + ND) {
    int j = i - NC;
    int n = j / 192, k = j - n * 192;
    Wd[j] = (k < 130) ? f2b(wih[n * 642 + 512 + k]) : (u16)0;
  }
}

// fco_w [130,1024] f32 -> bf16 WBy [256,1024], zero rows 130..255
__global__ void prep_wby(const float* __restrict__ fcow, u16* __restrict__ wby) {
  int i = blockIdx.x * 256 + threadIdx.x;   // 256*1024
  int n = i >> 10;
  wby[i] = (n < 130) ? f2b(fcow[i]) : (u16)0;
}

// prev matrix P[32768][192] bf16: row = t*2048 + e*128 + b, tt = e*16+t;
// P[row][k] = (tt>0 && k<130) ? target[b][tt-1][k] : 0.
__global__ void prep_prev(const float* __restrict__ target, u16* __restrict__ P) {
  int i = blockIdx.x * 256 + threadIdx.x;   // 32768 * 24 chunks of 8
  int row = i / 24;
  int c8  = i - row * 24;
  int k0 = c8 * 8;
  int t = row >> 11, m2 = row & 2047;
  int e = m2 >> 7, b = m2 & 127;
  int tt = e * 16 + t;
  u16x8 r;
  if (tt > 0 && k0 + 8 <= 130) {
    const float* trow = target + (size_t)(b * 256 + tt - 1) * 130 + k0;
#pragma unroll
    for (int q = 0; q < 8; ++q) r[q] = f2b(trow[q]);
  } else if (tt > 0 && k0 < 130) {
    const float* trow = target + (size_t)(b * 256 + tt - 1) * 130;
#pragma unroll
    for (int q = 0; q < 8; ++q) { int k = k0 + q; r[q] = (k < 130) ? f2b(trow[k]) : (u16)0; }
  } else {
#pragma unroll
    for (int q = 0; q < 8; ++q) r[q] = (u16)0;
  }
  *(u16x8*)&P[(size_t)row * 192 + k0] = r;
}

// ---------------------------------------------------------------------------
// GEMM core — r9 geometry (the verified 47.5us/533TF config): 128x128 tile,
// BK=32, 512 threads = 8 waves (4m x 2n of 32m x 64n, acc 2x4), mfma
// 16x16x32 bf16, f32 accum. 3-buffer counted-vmcnt K-loop (vmcnt(2): tile ks
// landed, ks+1 in flight, issue ks+2 after barrier). Both-sides XOR swizzle
// (chunk' = chunk ^ ((row>>1)&3)) -> measured 0 bank conflicts.
// r10's 4-wave 64x64 variant REVERTED: occupancy 28%, latency-exposed (-10%).
// ---------------------------------------------------------------------------
__device__ __forceinline__ void kloop3(
    const u16* gA, const u16* gB, int nk,
    u16* AsBase, u16* BsBase, int wave,
    int rdA, int rdB, f32x4 (&acc)[2][4])
{
  u16* Adst = AsBase + wave * 512;   // per-wave 16-row slab, linear dest
  u16* Bdst = BsBase + wave * 512;
  // prologue: tiles 0 and 1 in flight (nk >= 2 always here)
  gl16(gA,      Adst);        gl16(gB,      Bdst);
  gl16(gA + 32, Adst + 4096); gl16(gB + 32, Bdst + 4096);
  const u16* pA = gA + 64;
  const u16* pB = gB + 64;
  int cbuf = 0, nbuf = 2;
  for (int ks = 0; ks < nk; ++ks) {
    if (ks < nk - 1) asm volatile("s_waitcnt vmcnt(2)" : : : "memory");
    else             asm volatile("s_waitcnt vmcnt(0)" : : : "memory");
    __builtin_amdgcn_s_barrier();
    __builtin_amdgcn_sched_barrier(0);
    if (ks + 2 < nk) {
      gl16(pA, Adst + nbuf * 4096);
      gl16(pB, Bdst + nbuf * 4096);
      pA += 32; pB += 32;
    }
    const u16* Ab = AsBase + cbuf * 4096;
    const u16* Bb = BsBase + cbuf * 4096;
    frag8 af[2], bfr[4];
#pragma unroll
    for (int i = 0; i < 2; ++i)
      af[i] = *(const frag8*)&Ab[rdA + i * 512];
#pragma unroll
    for (int j = 0; j < 4; ++j)
      bfr[j] = *(const frag8*)&Bb[rdB + j * 512];
#pragma unroll
    for (int i = 0; i < 2; ++i)
#pragma unroll
      for (int j = 0; j < 4; ++j)
        acc[i][j] = __builtin_amdgcn_mfma_f32_16x16x32_bf16(af[i], bfr[j], acc[i][j], 0, 0, 0);
    cbuf = (cbuf == 2) ? 0 : cbuf + 1;
    nbuf = (nbuf == 2) ? 0 : nbuf + 1;
  }
}

// ---------------------------------------------------------------------------
// bt-GEMM: C[m][n] = sum_k A[m][k]*Bsel[n'][k].  A,B bf16.
//   Bsel/n' per 128-tile: n0<n_split -> B0,n'=n else B1,n'=n-n_split
// Epilogue modes:
//  1: t=tanh(acc+bias0[n]); n<1024 -> h1 else h2; write f32 (fout*) AND bf16 (out*)
//  2: out0(bf16)[m*3072+n] = acc + b2f(addmat[(m&2047)*3072+n])       [N=3072]
//  3: n<3072 -> out0+bias0 (gi2) ; else out1+bias1 (gh1)              [N=6144]
//  4: n<3072 -> out0+bias0 (gh2) ; 3072<=n<3202 -> y(f32) scatter     [N=3328]
// ---------------------------------------------------------------------------
__global__ __launch_bounds__(512, 6) void gemm_bt(
    const u16* __restrict__ A, int lda,
    const u16* __restrict__ B0, const u16* __restrict__ B1, int ldb, int n_split,
    int N, int K, int mode, int tstep, int axis,
    const float* __restrict__ bias0, const float* __restrict__ bias1,
    u16* __restrict__ out0, u16* __restrict__ out1,
    const u16* __restrict__ addmat,
    float* __restrict__ fout0, float* __restrict__ fout1)
{
  __shared__ u16 As[3 * 4096];
  __shared__ u16 Bs[3 * 4096];

  int bx, by;
  xcd_remap(axis, bx, by);

  const int tid = threadIdx.x;
  const int wave = tid >> 6;
  const int lane = tid & 63;
  const int m0 = by * 128;
  const int n0 = bx * 128;
  const int wm = (wave & 3) * 32;
  const int wn = (wave >> 2) * 64;
  const int lr = lane & 15;
  const int lq = lane >> 4;
  const int sw = (lr >> 1) & 3;                  // read-side swizzle
  const int rdA = (wm + lr) * 32 + ((lq ^ sw) << 3);
  const int rdB = (wn + lr) * 32 + ((lq ^ sw) << 3);

  const u16* Bsel;
  int nb0;
  if (n0 < n_split) { Bsel = B0; nb0 = n0; }
  else              { Bsel = B1; nb0 = n0 - n_split; }

  f32x4 acc[2][4] = {};

  // staging: row = wave*16 + (lane>>2), chunk pre-swizzled
  const int srow_g = wave * 16 + (lane >> 2);
  const int scol_g = (((lane & 3) ^ ((lane >> 3) & 3)) << 3);
  const u16* gA = &A[(size_t)(m0 + srow_g) * lda + scol_g];
  const u16* gB = &Bsel[(size_t)(nb0 + srow_g) * ldb + scol_g];

  kloop3(gA, gB, K >> 5, As, Bs, wave, rdA, rdB, acc);

  // C/D layout: col = lane&15 (n), row = (lane>>4)*4 + reg (m).
#pragma unroll
  for (int i = 0; i < 2; ++i) {
#pragma unroll
    for (int r = 0; r < 4; ++r) {
      int m = m0 + wm + i * 16 + lq * 4 + r;
#pragma unroll
      for (int j = 0; j < 4; ++j) {
        int n = n0 + wn + j * 16 + lr;
        float v = acc[i][j][r];
        if (mode == 1) {
          float t = ftanh(v + bias0[n]);
          if (n < 1024) { fout0[(size_t)m * 1024 + n] = t;          out0[(size_t)m * 1024 + n] = f2b(t); }
          else          { fout1[(size_t)m * 1024 + (n - 1024)] = t; out1[(size_t)m * 1024 + (n - 1024)] = f2b(t); }
        } else if (mode == 2) {
          out0[(size_t)m * 3072 + n] = f2b(v + b2f(addmat[(size_t)(m & 2047) * 3072 + n]));
        } else if (mode == 3) {
          if (n < 3072) out0[(size_t)m * 3072 + n] = f2b(v + bias0[n]);
          else          out1[(size_t)m * 3072 + (n - 3072)] = f2b(v + bias1[n - 3072]);
        } else { // mode 4
          if (n < 3072) {
            out0[(size_t)m * 3072 + n] = f2b(v + bias0[n]);
          } else if (n < 3202) {
            int d = n - 3072;
            int b = m & 127, e = m >> 7;
            fout0[(size_t)((b << 8) + (e << 4) + tstep) * 130 + d] = v + bias1[d];
          }
        }
      }
    }
  }
}

// ---------------------------------------------------------------------------
// Merged init GEMM: gic = c@Wc.T (K=512) | gh1 = h1@W1h.T | gh2 = h2@W2h.T
// (both K=1024). One 72x16 dispatch (axis-0 XCD partition) instead of three
// 384-block launches at 1.5 rounds each (~50% fill).
// ---------------------------------------------------------------------------
__global__ __launch_bounds__(512, 6) void gemm_init(
    const u16* __restrict__ cbf, const u16* __restrict__ h1b, const u16* __restrict__ h2b,
    const u16* __restrict__ Wc, const u16* __restrict__ W1h, const u16* __restrict__ W2h,
    const float* __restrict__ b1ih, const float* __restrict__ b1hh, const float* __restrict__ b2hh,
    u16* __restrict__ gic, u16* __restrict__ gh1, u16* __restrict__ gh2)
{
  __shared__ u16 As[3 * 4096];
  __shared__ u16 Bs[3 * 4096];

  int bx, by;
  xcd_remap(0, bx, by);

  const int tid = threadIdx.x;
  const int wave = tid >> 6;
  const int lane = tid & 63;
  const int m0 = by * 128;
  const int reg = bx / 24;
  const int nb0 = (bx - reg * 24) * 128;
  const int wm = (wave & 3) * 32;
  const int wn = (wave >> 2) * 64;
  const int lr = lane & 15;
  const int lq = lane >> 4;
  const int sw = (lr >> 1) & 3;
  const int rdA = (wm + lr) * 32 + ((lq ^ sw) << 3);
  const int rdB = (wn + lr) * 32 + ((lq ^ sw) << 3);

  const u16* A    = (reg == 0) ? cbf : (reg == 1) ? h1b : h2b;
  const u16* Bw   = (reg == 0) ? Wc  : (reg == 1) ? W1h : W2h;
  const float* bi = (reg == 0) ? b1ih : (reg == 1) ? b1hh : b2hh;
  u16* out        = (reg == 0) ? gic : (reg == 1) ? gh1 : gh2;
  const int ld    = (reg == 0) ? 512 : 1024;
  const int K     = (reg == 0) ? 512 : 1024;

  const int srow_g = wave * 16 + (lane >> 2);
  const int scol_g = (((lane & 3) ^ ((lane >> 3) & 3)) << 3);
  const u16* gA = &A[(size_t)(m0 + srow_g) * ld + scol_g];
  const u16* gB = &Bw[(size_t)(nb0 + srow_g) * ld + scol_g];

  f32x4 acc[2][4] = {};
  kloop3(gA, gB, K >> 5, As, Bs, wave, rdA, rdB, acc);

#pragma unroll
  for (int i = 0; i < 2; ++i) {
#pragma unroll
    for (int r = 0; r < 4; ++r) {
      int m = m0 + wm + i * 16 + lq * 4 + r;
#pragma unroll
      for (int j = 0; j < 4; ++j) {
        int n = nb0 + wn + j * 16 + lr;
        out[(size_t)m * 3072 + n] = f2b(acc[i][j][r] + bi[n]);
      }
    }
  }
}

// ---------------------------------------------------------------------------
// Fused step GEMM: gemm3(t) [gi2 = h1@W2i ; gh1' = h1@W1h] and gemm4(t-1)
// [gh2' = h2@W2h ; y = h2@WBy] in ONE dispatch. N = 9472 -> 74 x 16 = 1184
// blocks, axis-0 XCD partition (each XCD: ~9 x-tiles -> B-slice ~2.4MB,
// L2-resident). Regions by n0: [0,3072) gi2 | [3072,6144) gh1 |
// [6144,9216) gh2 | [9216,9472) y. K = 1024, lda = ldb = 1024.
// ---------------------------------------------------------------------------
__global__ __launch_bounds__(512, 6) void gemm_fused(
    const u16* __restrict__ A1, const u16* __restrict__ A2,
    const u16* __restrict__ W2i, const u16* __restrict__ W1h,
    const u16* __restrict__ W2h, const u16* __restrict__ WBy,
    const float* __restrict__ b_gi2, const float* __restrict__ b_gh1,
    const float* __restrict__ b_gh2, const float* __restrict__ b_y,
    u16* __restrict__ gi2, u16* __restrict__ gh1, u16* __restrict__ gh2,
    float* __restrict__ y, int tstep)
{
  __shared__ u16 As[3 * 4096];
  __shared__ u16 Bs[3 * 4096];

  int bx, by;
  xcd_remap(0, bx, by);

  const int tid = threadIdx.x;
  const int wave = tid >> 6;
  const int lane = tid & 63;
  const int m0 = by * 128;
  const int n0 = bx * 128;
  const int wm = (wave & 3) * 32;
  const int wn = (wave >> 2) * 64;
  const int lr = lane & 15;
  const int lq = lane >> 4;
  const int sw = (lr >> 1) & 3;
  const int rdA = (wm + lr) * 32 + ((lq ^ sw) << 3);
  const int rdB = (wn + lr) * 32 + ((lq ^ sw) << 3);

  const int reg = (n0 >= 9216) ? 3 : (n0 / 3072);
  const int nb0 = n0 - reg * 3072;
  const u16* A  = (reg < 2) ? A1 : A2;
  const u16* Bw = (reg == 0) ? W2i : (reg == 1) ? W1h : (reg == 2) ? W2h : WBy;
  const float* bias = (reg == 0) ? b_gi2 : (reg == 1) ? b_gh1 : (reg == 2) ? b_gh2 : b_y;

  const int srow_g = wave * 16 + (lane >> 2);
  const int scol_g = (((lane & 3) ^ ((lane >> 3) & 3)) << 3);
  const u16* gA = &A[(size_t)(m0 + srow_g) * 1024 + scol_g];
  const u16* gB = &Bw[(size_t)(nb0 + srow_g) * 1024 + scol_g];

  f32x4 acc[2][4] = {};
  kloop3(gA, gB, 32, As, Bs, wave, rdA, rdB, acc);

#pragma unroll
  for (int i = 0; i < 2; ++i) {
#pragma unroll
    for (int r = 0; r < 4; ++r) {
      int m = m0 + wm + i * 16 + lq * 4 + r;
#pragma unroll
      for (int j = 0; j < 4; ++j) {
        int nl = nb0 + wn + j * 16 + lr;
        float v = acc[i][j][r];
        if (reg == 0)      gi2[(size_t)m * 3072 + nl] = f2b(v + bias[nl]);
        else if (reg == 1) gh1[(size_t)m * 3072 + nl] = f2b(v + bias[nl]);
        else if (reg == 2) gh2[(size_t)m * 3072 + nl] = f2b(v + bias[nl]);
        else if (nl < 130) {
          int b = m & 127, e = m >> 7;
          y[(size_t)((b << 8) + (e << 4) + tstep) * 130 + nl] = v + bias[nl];
        }
      }
    }
  }
}

// ---------------------------------------------------------------------------
// Fused GRU combine: slot A = combine1(t) [h1 <- GRU1], slot B =
// combine2(t-1) [h2 <- GRU2]. h = (1-z)*n + z*h; gi/gh bf16 [2048,3072]
// (biases folded), h32 f32 master state (in place), hb16 bf16 shadow.
// ---------------------------------------------------------------------------
__global__ __launch_bounds__(256) void gru2(
    const u16* __restrict__ giA, const u16* __restrict__ ghA,
    float* __restrict__ hA, u16* __restrict__ hbA,
    const u16* __restrict__ giB, const u16* __restrict__ ghB,
    float* __restrict__ hB, u16* __restrict__ hbB,
    int doA, int doB)
{
  int blk = blockIdx.x;
  const u16 *gi, *gh; float* h32; u16* hb16;
  if (blk < 1024) { if (!doA) return; gi = giA; gh = ghA; h32 = hA; hb16 = hbA; }
  else { if (!doB) return; gi = giB; gh = ghB; h32 = hB; hb16 = hbB; blk -= 1024; }
  int idx = blk * 256 + threadIdx.x;   // 0 .. 2048*128-1
  int m = idx >> 7;
  int j0 = (idx & 127) << 3;
  const size_t gb = (size_t)m * 3072 + j0;
  const size_t hb = (size_t)m * 1024 + j0;
  u16x8 ir = *(const u16x8*)&gi[gb];
  u16x8 iz = *(const u16x8*)&gi[gb + 1024];
  u16x8 in_ = *(const u16x8*)&gi[gb + 2048];
  u16x8 hr = *(const u16x8*)&gh[gb];
  u16x8 hz = *(const u16x8*)&gh[gb + 1024];
  u16x8 hn = *(const u16x8*)&gh[gb + 2048];
  f32x4 h0 = *(const f32x4*)&h32[hb];
  f32x4 h1v = *(const f32x4*)&h32[hb + 4];
  f32x4 o0, o1;
  u16x8 ob;
#pragma unroll
  for (int q = 0; q < 8; ++q) {
    float r = 1.f / (1.f + __expf(-(b2f(ir[q]) + b2f(hr[q]))));
    float z = 1.f / (1.f + __expf(-(b2f(iz[q]) + b2f(hz[q]))));
    float nn = ftanh(b2f(in_[q]) + r * b2f(hn[q]));
    float hh = (q < 4) ? h0[q & 3] : h1v[q & 3];
    float res = (1.f - z) * nn + z * hh;
    if (q < 4) o0[q & 3] = res; else o1[q & 3] = res;
    ob[q] = f2b(res);
  }
  *(f32x4*)&h32[hb] = o0;
  *(f32x4*)&h32[hb + 4] = o1;
  *(u16x8*)&hb16[hb] = ob;
}

// ---------------------------------------------------------------------------
extern "C" void kernel_launch(void* const* d_in, const int* in_sizes, int n_in,
                              void* d_out, int out_size, void* d_ws, size_t ws_size,
                              hipStream_t stream)
{
  const float* c      = (const float*)d_in[0];
  const float* target = (const float*)d_in[1];
  const float* fiw    = (const float*)d_in[4];
  const float* fib    = (const float*)d_in[5];
  const float* g1wih  = (const float*)d_in[6];
  const float* g1whh  = (const float*)d_in[7];
  const float* g1bih  = (const float*)d_in[8];
  const float* g1bhh  = (const float*)d_in[9];
  const float* g2wih  = (const float*)d_in[10];
  const float* g2whh  = (const float*)d_in[11];
  const float* g2bih  = (const float*)d_in[12];
  const float* g2bhh  = (const float*)d_in[13];
  const float* fcow   = (const float*)d_in[14];
  const float* fcob   = (const float*)d_in[15];
  float* out = (float*)d_out;

  char* wsp = (char*)d_ws;
  size_t off = 0;
  auto takeb = [&](size_t bytes) {
    void* p = (void*)(wsp + off);
    off += bytes;
    off = (off + 255) & ~(size_t)255;
    return p;
  };
  float* h1f = (float*)takeb((size_t)2048 * 1024 * 4);
  float* h2f = (float*)takeb((size_t)2048 * 1024 * 4);
  u16* h1b   = (u16*)takeb((size_t)2048 * 1024 * 2);
  u16* h2b   = (u16*)takeb((size_t)2048 * 1024 * 2);
  u16* gic   = (u16*)takeb((size_t)2048 * 3072 * 2);
  u16* gib   = (u16*)takeb((size_t)2048 * 3072 * 2);
  u16* gh1   = (u16*)takeb((size_t)2048 * 3072 * 2);
  u16* gh2   = (u16*)takeb((size_t)2048 * 3072 * 2);
  u16* cbf   = (u16*)takeb((size_t)2048 * 512 * 2);
  u16* Wfi   = (u16*)takeb((size_t)2048 * 512 * 2);
  u16* Wc    = (u16*)takeb((size_t)3072 * 512 * 2);
  u16* Wd    = (u16*)takeb((size_t)3072 * 192 * 2);
  u16* W1h   = (u16*)takeb((size_t)3072 * 1024 * 2);
  u16* W2i   = (u16*)takeb((size_t)3072 * 1024 * 2);
  u16* W2h   = (u16*)takeb((size_t)3072 * 1024 * 2);
  u16* WBy   = (u16*)takeb((size_t)256 * 1024 * 2);
  u16* P     = (u16*)takeb((size_t)32768 * 192 * 2);   // prev matrix, all t
  const size_t GI1_BYTES = (size_t)16 * 2048 * 3072 * 2;
  u16* gi1 = nullptr;
  if (ws_size >= off + GI1_BYTES + 256) gi1 = (u16*)takeb(GI1_BYTES);
  (void)in_sizes; (void)n_in; (void)out_size;

  const int BIG = 1 << 30;   // n_split sentinel: always B0

  // --- one-time prep: conversions to bf16 ---
  cvt2<<<8192, 256, 0, stream>>>(c, fiw, cbf, Wfi);
  cvt3<<<36864, 256, 0, stream>>>(g1whh, g2wih, g2whh, W1h, W2i, W2h);
  prep_w1 <<<8448, 256, 0, stream>>>(g1wih, Wc, Wd);
  prep_wby<<<1024, 256, 0, stream>>>(fcow, WBy);
  prep_prev<<<3072, 256, 0, stream>>>(target, P);

  // --- init ---
  // h1,h2 = tanh(c @ fiw.T + fib)  (f32 + bf16 shadow)
  gemm_bt<<<dim3(16, 16), 512, 0, stream>>>(cbf, 512, Wfi, nullptr, 512, BIG,
                                            2048, 512, 1, 0, 0, fib, nullptr,
                                            h1b, h2b, nullptr, h1f, h2f);
  // gic | gh1 | gh2 in one dispatch
  gemm_init<<<dim3(72, 16), 512, 0, stream>>>(cbf, h1b, h2b, Wc, W1h, W2h,
                                              g1bih, g1bhh, g2bhh, gic, gh1, gh2);

  if (gi1 != nullptr) {
    // gi1 for ALL t: gi1_all = P @ Wd.T + gic (row-broadcast). axis=1:
    // each XCD owns a contiguous m-range -> A-slice ~1.6MB + B 1.2MB L2-fit.
    gemm_bt<<<dim3(24, 256), 512, 0, stream>>>(P, 192, Wd, nullptr, 192, BIG,
                                               3072, 192, 2, 0, 1, nullptr, nullptr,
                                               gi1, nullptr, gic, nullptr, nullptr);

    // --- recurrence: alternating C(t) -> G(t), 2 dispatches per step ---
    gru2<<<2048, 256, 0, stream>>>(gi1, gh1, h1f, h1b, nullptr, nullptr, nullptr, nullptr, 1, 0);
    gemm_bt<<<dim3(48, 16), 512, 0, stream>>>(h1b, 1024, W2i, W1h, 1024, 3072,
                                              6144, 1024, 3, 0, 0, g2bih, g1bhh,
                                              gib, gh1, nullptr, nullptr, nullptr);
    for (int t = 1; t < 16; ++t) {
      // C(t): combine1(t) [gi1_t, gh1] + combine2(t-1) [gi2, gh2]
      gru2<<<2048, 256, 0, stream>>>(gi1 + (size_t)t * 2048 * 3072, gh1, h1f, h1b,
                                     gib, gh2, h2f, h2b, 1, 1);
      // G(t): gemm3(t) + gemm4(t-1); y uses tstep = t-1
      gemm_fused<<<dim3(74, 16), 512, 0, stream>>>(h1b, h2b, W2i, W1h, W2h, WBy,
                                                   g2bih, g1bhh, g2bhh, fcob,
                                                   gib, gh1, gh2, out, t - 1);
    }
    // C(16): combine2(15) only
    gru2<<<2048, 256, 0, stream>>>(nullptr, nullptr, nullptr, nullptr,
                                   gib, gh2, h2f, h2b, 0, 1);
    // G(16): gemm4(15): gh2' (discarded) + y(15)
    gemm_bt<<<dim3(26, 16), 512, 0, stream>>>(h2b, 1024, W2h, WBy, 1024, 3072,
                                              3328, 1024, 4, 15, 0, g2bhh, fcob,
                                              gh2, nullptr, nullptr, out, nullptr);
  } else {
    // fallback (small ws): per-step sequence, gi1 from P slice
    for (int t = 0; t < 16; ++t) {
      gemm_bt<<<dim3(24, 16), 512, 0, stream>>>(P + (size_t)t * 2048 * 192, 192, Wd, nullptr, 192, BIG,
                                                3072, 192, 2, 0, 0, nullptr, nullptr,
                                                gib, nullptr, gic, nullptr, nullptr);
      gru2<<<2048, 256, 0, stream>>>(gib, gh1, h1f, h1b, nullptr, nullptr, nullptr, nullptr, 1, 0);
      gemm_bt<<<dim3(48, 16), 512, 0, stream>>>(h1b, 1024, W2i, W1h, 1024, 3072,
                                                6144, 1024, 3, 0, 0, g2bih, g1bhh,
                                                gib, gh1, nullptr, nullptr, nullptr);
      gru2<<<2048, 256, 0, stream>>>(gib, gh2, h2f, h2b, nullptr, nullptr, nullptr, nullptr, 1, 0);
      gemm_bt<<<dim3(26, 16), 512, 0, stream>>>(h2b, 1024, W2h, WBy, 1024, 3072,
                                                3328, 1024, 4, t, 0, g2bhh, fcob,
                                                gh2, nullptr, nullptr, out, nullptr);
    }
  }
}

// Round 7
// 1803.017 us; speedup vs baseline: 1.3210x; 1.0492x over previous
//
#include <hip/hip_runtime.h>

typedef unsigned short u16;
typedef __attribute__((ext_vector_type(8))) short frag8;
typedef __attribute__((ext_vector_type(4))) float f32x4;
typedef __attribute__((ext_vector_type(8))) unsigned short u16x8;

// address-space typedefs for global_load_lds
typedef __attribute__((address_space(1))) const void GV;
typedef __attribute__((address_space(3))) void LV;

__device__ __forceinline__ void gl16(const u16* g, u16* l) {
  // async global->LDS, 16B per lane; LDS dest = wave-uniform base + lane*16
  __builtin_amdgcn_global_load_lds((GV*)g, (LV*)l, 16, 0, 0);
}

__device__ __forceinline__ float b2f(u16 u) {
  union { unsigned int i; float f; } v; v.i = ((unsigned int)u) << 16; return v.f;
}
__device__ __forceinline__ u16 f2b(float f) {
  union { float f; unsigned int i; } v; v.f = f;
  unsigned int x = v.i;
  x += 0x7fffu + ((x >> 16) & 1u);
  return (u16)(x >> 16);
}
// fast tanh: 1 - 2/(e^{2x}+1). Large +x: e=inf -> 1; large -x: e=0 -> -1.
__device__ __forceinline__ float ftanh(float x) {
  float e = __expf(2.f * x);
  return 1.f - 2.f / (e + 1.f);
}

// ---------------------------------------------------------------------------
// XCD-aware blockIdx remap (T1, m204 bijective form). axis 0: each XCD owns a
// contiguous x-range (B-slice fits its 4MB L2). axis 1: contiguous y-range.
// Perf-only bijection. (r11: confirmed gains on once-per-launch GEMMs.)
// ---------------------------------------------------------------------------
__device__ __forceinline__ void xcd_remap(int axis, int& bx, int& by) {
  const int nx = gridDim.x, ny = gridDim.y;
  const int nwg = nx * ny;
  const int bid = blockIdx.x + nx * blockIdx.y;
  const int q = nwg >> 3, r = nwg & 7;
  const int xcd = bid & 7, i = bid >> 3;
  const int rem = (xcd < r ? xcd * (q + 1) : r * (q + 1) + (xcd - r) * q) + i;
  if (axis == 0) { bx = rem / ny; by = rem - bx * ny; }
  else           { by = rem / nx; bx = rem - by * nx; }
}

// ---------------------------------------------------------------------------
// One-shot prep: every bf16 conversion + the prev matrix P, in ONE dispatch.
// P[32768][192]: row = t*2048 + e*128 + b, tt = e*16 + t;
// P[row][k] = (tt>0 && k<130) ? target[b][tt-1][k] : 0.
// ---------------------------------------------------------------------------
__global__ void mega_prep(const float* __restrict__ c, const float* __restrict__ fiw,
                          const float* __restrict__ g1whh, const float* __restrict__ g2wih,
                          const float* __restrict__ g2whh, const float* __restrict__ g1wih,
                          const float* __restrict__ fcow, const float* __restrict__ target,
                          u16* __restrict__ cbf, u16* __restrict__ Wfi, u16* __restrict__ W1h,
                          u16* __restrict__ W2i, u16* __restrict__ W2h, u16* __restrict__ Wc,
                          u16* __restrict__ Wd, u16* __restrict__ WBy, u16* __restrict__ P)
{
  int i = blockIdx.x * 256 + threadIdx.x;       // 57600 blocks x 256 = 14,745,600
  if (i < 1048576) { cbf[i] = f2b(c[i]); return; }
  i -= 1048576;
  if (i < 1048576) { Wfi[i] = f2b(fiw[i]); return; }
  i -= 1048576;
  if (i < 3145728) { W1h[i] = f2b(g1whh[i]); return; }
  i -= 3145728;
  if (i < 3145728) { W2i[i] = f2b(g2wih[i]); return; }
  i -= 3145728;
  if (i < 3145728) { W2h[i] = f2b(g2whh[i]); return; }
  i -= 3145728;
  if (i < 1572864) { int n = i >> 9, k = i & 511; Wc[i] = f2b(g1wih[n * 642 + k]); return; }
  i -= 1572864;
  if (i < 589824) {  // Wd [3072][192], zero-pad k>=130
    int n = i / 192, k = i - n * 192;
    Wd[i] = (k < 130) ? f2b(g1wih[n * 642 + 512 + k]) : (u16)0;
    return;
  }
  i -= 589824;
  if (i < 262144) { int n = i >> 10; WBy[i] = (n < 130) ? f2b(fcow[i]) : (u16)0; return; }
  i -= 262144;
  {  // P: 786432 items, 8 elems each
    int row = i / 24;
    int k0 = (i - row * 24) * 8;
    int t = row >> 11, m2 = row & 2047;
    int e = m2 >> 7, b = m2 & 127;
    int tt = e * 16 + t;
    u16x8 r;
    if (tt > 0 && k0 + 8 <= 130) {
      const float* trow = target + (size_t)(b * 256 + tt - 1) * 130 + k0;
#pragma unroll
      for (int q = 0; q < 8; ++q) r[q] = f2b(trow[q]);
    } else if (tt > 0 && k0 < 130) {
      const float* trow = target + (size_t)(b * 256 + tt - 1) * 130;
#pragma unroll
      for (int q = 0; q < 8; ++q) { int k = k0 + q; r[q] = (k < 130) ? f2b(trow[k]) : (u16)0; }
    } else {
#pragma unroll
      for (int q = 0; q < 8; ++q) r[q] = (u16)0;
    }
    *(u16x8*)&P[(size_t)row * 192 + k0] = r;
  }
}

// ---------------------------------------------------------------------------
// GEMM core — r9-verified geometry: 128x128 tile, BK=32, 512 threads = 8
// waves (4m x 2n of 32m x 64n, acc 2x4), mfma 16x16x32 bf16, f32 accum.
// 3-buffer counted-vmcnt K-loop (vmcnt(2)); both-sides XOR swizzle
// (chunk' = chunk ^ ((row>>1)&3)) -> 0 bank conflicts measured.
// ---------------------------------------------------------------------------
__device__ __forceinline__ void kloop3(
    const u16* gA, const u16* gB, int nk,
    u16* AsBase, u16* BsBase, int wave,
    int rdA, int rdB, f32x4 (&acc)[2][4])
{
  u16* Adst = AsBase + wave * 512;   // per-wave 16-row slab, linear dest
  u16* Bdst = BsBase + wave * 512;
  gl16(gA,      Adst);        gl16(gB,      Bdst);
  gl16(gA + 32, Adst + 4096); gl16(gB + 32, Bdst + 4096);
  const u16* pA = gA + 64;
  const u16* pB = gB + 64;
  int cbuf = 0, nbuf = 2;
  for (int ks = 0; ks < nk; ++ks) {
    if (ks < nk - 1) asm volatile("s_waitcnt vmcnt(2)" : : : "memory");
    else             asm volatile("s_waitcnt vmcnt(0)" : : : "memory");
    __builtin_amdgcn_s_barrier();
    __builtin_amdgcn_sched_barrier(0);
    if (ks + 2 < nk) {
      gl16(pA, Adst + nbuf * 4096);
      gl16(pB, Bdst + nbuf * 4096);
      pA += 32; pB += 32;
    }
    const u16* Ab = AsBase + cbuf * 4096;
    const u16* Bb = BsBase + cbuf * 4096;
    frag8 af[2], bfr[4];
#pragma unroll
    for (int i = 0; i < 2; ++i)
      af[i] = *(const frag8*)&Ab[rdA + i * 512];
#pragma unroll
    for (int j = 0; j < 4; ++j)
      bfr[j] = *(const frag8*)&Bb[rdB + j * 512];
#pragma unroll
    for (int i = 0; i < 2; ++i)
#pragma unroll
      for (int j = 0; j < 4; ++j)
        acc[i][j] = __builtin_amdgcn_mfma_f32_16x16x32_bf16(af[i], bfr[j], acc[i][j], 0, 0, 0);
    cbuf = (cbuf == 2) ? 0 : cbuf + 1;
    nbuf = (nbuf == 2) ? 0 : nbuf + 1;
  }
}

// fragment-read / staging offsets shared by all GEMM kernels
struct GeomT { int wave, lane, wm, wn, lr, lq, rdA, rdB, srow, scol; };
__device__ __forceinline__ GeomT geom(int tid) {
  GeomT g;
  g.wave = tid >> 6; g.lane = tid & 63;
  g.wm = (g.wave & 3) * 32; g.wn = (g.wave >> 2) * 64;
  g.lr = g.lane & 15; g.lq = g.lane >> 4;
  int sw = (g.lr >> 1) & 3;
  g.rdA = (g.wm + g.lr) * 32 + ((g.lq ^ sw) << 3);
  g.rdB = (g.wn + g.lr) * 32 + ((g.lq ^ sw) << 3);
  g.srow = g.wave * 16 + (g.lane >> 2);
  g.scol = (((g.lane & 3) ^ ((g.lane >> 3) & 3)) << 3);
  return g;
}

// ---------------------------------------------------------------------------
// bt-GEMM (FALLBACK path only): modes 2/3/4 as in r11.
// ---------------------------------------------------------------------------
__global__ __launch_bounds__(512, 6) void gemm_bt(
    const u16* __restrict__ A, int lda,
    const u16* __restrict__ B0, const u16* __restrict__ B1, int ldb, int n_split,
    int N, int K, int mode, int tstep, int axis,
    const float* __restrict__ bias0, const float* __restrict__ bias1,
    u16* __restrict__ out0, u16* __restrict__ out1,
    const u16* __restrict__ addmat,
    float* __restrict__ fout0, float* __restrict__ fout1)
{
  __shared__ u16 As[3 * 4096];
  __shared__ u16 Bs[3 * 4096];
  int bx, by; xcd_remap(axis, bx, by);
  GeomT g = geom(threadIdx.x);
  const int m0 = by * 128, n0 = bx * 128;

  const u16* Bsel; int nb0;
  if (n0 < n_split) { Bsel = B0; nb0 = n0; }
  else              { Bsel = B1; nb0 = n0 - n_split; }

  f32x4 acc[2][4] = {};
  const u16* gA = &A[(size_t)(m0 + g.srow) * lda + g.scol];
  const u16* gB = &Bsel[(size_t)(nb0 + g.srow) * ldb + g.scol];
  kloop3(gA, gB, K >> 5, As, Bs, g.wave, g.rdA, g.rdB, acc);

#pragma unroll
  for (int i = 0; i < 2; ++i) {
#pragma unroll
    for (int r = 0; r < 4; ++r) {
      int m = m0 + g.wm + i * 16 + g.lq * 4 + r;
#pragma unroll
      for (int j = 0; j < 4; ++j) {
        int n = n0 + g.wn + j * 16 + g.lr;
        float v = acc[i][j][r];
        if (mode == 2) {
          out0[(size_t)m * 3072 + n] = f2b(v + b2f(addmat[(size_t)(m & 2047) * 3072 + n]));
        } else if (mode == 3) {
          if (n < 3072) out0[(size_t)m * 3072 + n] = f2b(v + bias0[n]);
          else          out1[(size_t)m * 3072 + (n - 3072)] = f2b(v + bias1[n - 3072]);
        } else { // mode 4
          if (n < 3072) {
            out0[(size_t)m * 3072 + n] = f2b(v + bias0[n]);
          } else if (n < 3202) {
            int d = n - 3072;
            int b = m & 127, e = m >> 7;
            fout0[(size_t)((b << 8) + (e << 4) + tstep) * 130 + d] = v + bias1[d];
          }
        }
      }
    }
  }
}

// ---------------------------------------------------------------------------
// Init GEMM A: bx<16: {h1,h2} = tanh(c@Wfi.T + fib) (f32 + bf16 shadow);
// bx in [16,40): gic = c@Wc.T + g1bih.  Both K=512, A=cbf.
// ---------------------------------------------------------------------------
__global__ __launch_bounds__(512, 6) void gemm_A(
    const u16* __restrict__ cbf, const u16* __restrict__ Wfi, const u16* __restrict__ Wc,
    const float* __restrict__ fib, const float* __restrict__ g1bih,
    float* __restrict__ h1f, float* __restrict__ h2f,
    u16* __restrict__ h1b, u16* __restrict__ h2b, u16* __restrict__ gic)
{
  __shared__ u16 As[3 * 4096];
  __shared__ u16 Bs[3 * 4096];
  int bx, by; xcd_remap(0, bx, by);
  GeomT g = geom(threadIdx.x);
  const int m0 = by * 128;
  const int isInit = (bx < 16);
  const int nb0 = isInit ? bx * 128 : (bx - 16) * 128;
  const u16* Bw = isInit ? Wfi : Wc;

  f32x4 acc[2][4] = {};
  const u16* gA = &cbf[(size_t)(m0 + g.srow) * 512 + g.scol];
  const u16* gB = &Bw[(size_t)(nb0 + g.srow) * 512 + g.scol];
  kloop3(gA, gB, 16, As, Bs, g.wave, g.rdA, g.rdB, acc);

#pragma unroll
  for (int i = 0; i < 2; ++i) {
#pragma unroll
    for (int r = 0; r < 4; ++r) {
      int m = m0 + g.wm + i * 16 + g.lq * 4 + r;
#pragma unroll
      for (int j = 0; j < 4; ++j) {
        int n = nb0 + g.wn + j * 16 + g.lr;
        float v = acc[i][j][r];
        if (isInit) {
          float t = ftanh(v + fib[n]);
          if (n < 1024) { h1f[(size_t)m * 1024 + n] = t;          h1b[(size_t)m * 1024 + n] = f2b(t); }
          else          { h2f[(size_t)m * 1024 + (n - 1024)] = t; h2b[(size_t)m * 1024 + (n - 1024)] = f2b(t); }
        } else {
          gic[(size_t)m * 3072 + n] = f2b(v + g1bih[n]);
        }
      }
    }
  }
}

// ---------------------------------------------------------------------------
// Init GEMM B: bx<24: gh1 = h1@W1h+b1hh | <48: gh2 = h2@W2h+b2hh |
// <72: gi1(0) = P[t=0]@Wd.T + gic (K=192). Grid 48x16 in fallback (no gi1).
// ---------------------------------------------------------------------------
__global__ __launch_bounds__(512, 6) void gemm_B(
    const u16* __restrict__ h1b, const u16* __restrict__ h2b, const u16* __restrict__ P,
    const u16* __restrict__ W1h, const u16* __restrict__ W2h, const u16* __restrict__ Wd,
    const float* __restrict__ b1hh, const float* __restrict__ b2hh,
    const u16* __restrict__ gic,
    u16* __restrict__ gh1, u16* __restrict__ gh2, u16* __restrict__ gi1w)
{
  __shared__ u16 As[3 * 4096];
  __shared__ u16 Bs[3 * 4096];
  int bx, by; xcd_remap(0, bx, by);
  GeomT g = geom(threadIdx.x);
  const int m0 = by * 128;
  int reg, nb0;
  const u16 *A, *Bw; int ld, K;
  if (bx < 24)      { reg = 0; nb0 = bx * 128;        A = h1b; Bw = W1h; ld = 1024; K = 1024; }
  else if (bx < 48) { reg = 1; nb0 = (bx - 24) * 128; A = h2b; Bw = W2h; ld = 1024; K = 1024; }
  else              { reg = 2; nb0 = (bx - 48) * 128; A = P;   Bw = Wd;  ld = 192;  K = 192;  }

  f32x4 acc[2][4] = {};
  const u16* gA = &A[(size_t)(m0 + g.srow) * ld + g.scol];
  const u16* gB = &Bw[(size_t)(nb0 + g.srow) * ld + g.scol];
  kloop3(gA, gB, K >> 5, As, Bs, g.wave, g.rdA, g.rdB, acc);

#pragma unroll
  for (int i = 0; i < 2; ++i) {
#pragma unroll
    for (int r = 0; r < 4; ++r) {
      int m = m0 + g.wm + i * 16 + g.lq * 4 + r;
#pragma unroll
      for (int j = 0; j < 4; ++j) {
        int n = nb0 + g.wn + j * 16 + g.lr;
        float v = acc[i][j][r];
        if (reg == 0)      gh1[(size_t)m * 3072 + n] = f2b(v + b1hh[n]);
        else if (reg == 1) gh2[(size_t)m * 3072 + n] = f2b(v + b2hh[n]);
        else               gi1w[(size_t)m * 3072 + n] = f2b(v + b2f(gic[(size_t)m * 3072 + n]));
      }
    }
  }
}

// ---------------------------------------------------------------------------
// Fused step GEMM with 5 regions selected by x-tile thresholds c0..c3:
//   [0,c0)   reg0 gi2  = h1@W2i + b_gi2          (K=1024)
//   [c0,c1)  reg1 gh1' = h1@W1h + b_gh1          (K=1024)
//   [c1,c2)  reg2 gh2' = h2@W2h + b_gh2          (K=1024)
//   [c2,c3)  reg3 y(tstep) = h2@WBy + fcob, f32 scatter (K=1024)
//   [c3,gx)  reg4 gi1(t+1) = Pt@Wd.T + gic       (K=192) -> rolling g1A
// Rolling g1A is safe: C(t) reads it strictly before G(t) overwrites (same
// stream). Region configs:
//   G(0)     = {24,48,48,48}, gx=72  (gi2, gh1', gi1)
//   G(1..14) = {24,48,72,74}, gx=98  (all five)
//   G(15)    = {24,24,48,50}, gx=50  (gi2(15), gh2(15), y(14))
//     ^ r13 FIX: r12 used {24,24,24,26} which DROPPED gh2(15); C(16)'s
//       combine2(15) then consumed stale gh2(14) -> absmax 1.9e-2 fail.
//       gh1'(16)/gi1(16) remain correctly dropped (no consumers).
//   G(16)    = {0,0,0,2},    gx=2   (y(15) only)
// ---------------------------------------------------------------------------
__global__ __launch_bounds__(512, 6) void gemm_fused(
    const u16* __restrict__ h1b, const u16* __restrict__ h2b, const u16* __restrict__ Pt,
    const u16* __restrict__ W2i, const u16* __restrict__ W1h, const u16* __restrict__ W2h,
    const u16* __restrict__ WBy, const u16* __restrict__ Wd,
    const float* __restrict__ b_gi2, const float* __restrict__ b_gh1,
    const float* __restrict__ b_gh2, const float* __restrict__ b_y,
    const u16* __restrict__ gic,
    u16* __restrict__ gi2, u16* __restrict__ gh1, u16* __restrict__ gh2,
    float* __restrict__ y, u16* __restrict__ gi1w,
    int c0, int c1, int c2, int c3, int tstep)
{
  __shared__ u16 As[3 * 4096];
  __shared__ u16 Bs[3 * 4096];
  int bx, by; xcd_remap(0, bx, by);
  GeomT g = geom(threadIdx.x);
  const int m0 = by * 128;
  int reg, nb0;
  const u16 *A, *Bw; int ld, K;
  if (bx < c0)      { reg = 0; nb0 = bx * 128;        A = h1b; Bw = W2i; ld = 1024; K = 1024; }
  else if (bx < c1) { reg = 1; nb0 = (bx - c0) * 128; A = h1b; Bw = W1h; ld = 1024; K = 1024; }
  else if (bx < c2) { reg = 2; nb0 = (bx - c1) * 128; A = h2b; Bw = W2h; ld = 1024; K = 1024; }
  else if (bx < c3) { reg = 3; nb0 = (bx - c2) * 128; A = h2b; Bw = WBy; ld = 1024; K = 1024; }
  else              { reg = 4; nb0 = (bx - c3) * 128; A = Pt;  Bw = Wd;  ld = 192;  K = 192;  }

  f32x4 acc[2][4] = {};
  const u16* gA = &A[(size_t)(m0 + g.srow) * ld + g.scol];
  const u16* gB = &Bw[(size_t)(nb0 + g.srow) * ld + g.scol];
  kloop3(gA, gB, K >> 5, As, Bs, g.wave, g.rdA, g.rdB, acc);

#pragma unroll
  for (int i = 0; i < 2; ++i) {
#pragma unroll
    for (int r = 0; r < 4; ++r) {
      int m = m0 + g.wm + i * 16 + g.lq * 4 + r;
#pragma unroll
      for (int j = 0; j < 4; ++j) {
        int nl = nb0 + g.wn + j * 16 + g.lr;
        float v = acc[i][j][r];
        if (reg == 0)      gi2[(size_t)m * 3072 + nl] = f2b(v + b_gi2[nl]);
        else if (reg == 1) gh1[(size_t)m * 3072 + nl] = f2b(v + b_gh1[nl]);
        else if (reg == 2) gh2[(size_t)m * 3072 + nl] = f2b(v + b_gh2[nl]);
        else if (reg == 3) {
          if (nl < 130) {
            int b = m & 127, e = m >> 7;
            y[(size_t)((b << 8) + (e << 4) + tstep) * 130 + nl] = v + b_y[nl];
          }
        } else {
          gi1w[(size_t)m * 3072 + nl] = f2b(v + b2f(gic[(size_t)m * 3072 + nl]));
        }
      }
    }
  }
}

// ---------------------------------------------------------------------------
// Fused GRU combine: slot A = combine1(t) [h1 <- GRU1], slot B =
// combine2(t-1) [h2 <- GRU2]. h = (1-z)*n + z*h; gi/gh bf16 [2048,3072]
// (biases folded), h32 f32 master state (in place), hb16 bf16 shadow.
// ---------------------------------------------------------------------------
__global__ __launch_bounds__(256) void gru2(
    const u16* __restrict__ giA, const u16* __restrict__ ghA,
    float* __restrict__ hA, u16* __restrict__ hbA,
    const u16* __restrict__ giB, const u16* __restrict__ ghB,
    float* __restrict__ hB, u16* __restrict__ hbB,
    int doA, int doB)
{
  int blk = blockIdx.x;
  const u16 *gi, *gh; float* h32; u16* hb16;
  if (blk < 1024) { if (!doA) return; gi = giA; gh = ghA; h32 = hA; hb16 = hbA; }
  else { if (!doB) return; gi = giB; gh = ghB; h32 = hB; hb16 = hbB; blk -= 1024; }
  int idx = blk * 256 + threadIdx.x;   // 0 .. 2048*128-1
  int m = idx >> 7;
  int j0 = (idx & 127) << 3;
  const size_t gb = (size_t)m * 3072 + j0;
  const size_t hb = (size_t)m * 1024 + j0;
  u16x8 ir = *(const u16x8*)&gi[gb];
  u16x8 iz = *(const u16x8*)&gi[gb + 1024];
  u16x8 in_ = *(const u16x8*)&gi[gb + 2048];
  u16x8 hr = *(const u16x8*)&gh[gb];
  u16x8 hz = *(const u16x8*)&gh[gb + 1024];
  u16x8 hn = *(const u16x8*)&gh[gb + 2048];
  f32x4 h0 = *(const f32x4*)&h32[hb];
  f32x4 h1v = *(const f32x4*)&h32[hb + 4];
  f32x4 o0, o1;
  u16x8 ob;
#pragma unroll
  for (int q = 0; q < 8; ++q) {
    float r = 1.f / (1.f + __expf(-(b2f(ir[q]) + b2f(hr[q]))));
    float z = 1.f / (1.f + __expf(-(b2f(iz[q]) + b2f(hz[q]))));
    float nn = ftanh(b2f(in_[q]) + r * b2f(hn[q]));
    float hh = (q < 4) ? h0[q & 3] : h1v[q & 3];
    float res = (1.f - z) * nn + z * hh;
    if (q < 4) o0[q & 3] = res; else o1[q & 3] = res;
    ob[q] = f2b(res);
  }
  *(f32x4*)&h32[hb] = o0;
  *(f32x4*)&h32[hb + 4] = o1;
  *(u16x8*)&hb16[hb] = ob;
}

// ---------------------------------------------------------------------------
extern "C" void kernel_launch(void* const* d_in, const int* in_sizes, int n_in,
                              void* d_out, int out_size, void* d_ws, size_t ws_size,
                              hipStream_t stream)
{
  const float* c      = (const float*)d_in[0];
  const float* target = (const float*)d_in[1];
  const float* fiw    = (const float*)d_in[4];
  const float* fib    = (const float*)d_in[5];
  const float* g1wih  = (const float*)d_in[6];
  const float* g1whh  = (const float*)d_in[7];
  const float* g1bih  = (const float*)d_in[8];
  const float* g1bhh  = (const float*)d_in[9];
  const float* g2wih  = (const float*)d_in[10];
  const float* g2whh  = (const float*)d_in[11];
  const float* g2bih  = (const float*)d_in[12];
  const float* g2bhh  = (const float*)d_in[13];
  const float* fcow   = (const float*)d_in[14];
  const float* fcob   = (const float*)d_in[15];
  float* out = (float*)d_out;

  char* wsp = (char*)d_ws;
  size_t off = 0;
  auto takeb = [&](size_t bytes) {
    void* p = (void*)(wsp + off);
    off += bytes;
    off = (off + 255) & ~(size_t)255;
    return p;
  };
  float* h1f = (float*)takeb((size_t)2048 * 1024 * 4);
  float* h2f = (float*)takeb((size_t)2048 * 1024 * 4);
  u16* h1b   = (u16*)takeb((size_t)2048 * 1024 * 2);
  u16* h2b   = (u16*)takeb((size_t)2048 * 1024 * 2);
  u16* gic   = (u16*)takeb((size_t)2048 * 3072 * 2);
  u16* gib   = (u16*)takeb((size_t)2048 * 3072 * 2);
  u16* gh1   = (u16*)takeb((size_t)2048 * 3072 * 2);
  u16* gh2   = (u16*)takeb((size_t)2048 * 3072 * 2);
  u16* cbf   = (u16*)takeb((size_t)2048 * 512 * 2);
  u16* Wfi   = (u16*)takeb((size_t)2048 * 512 * 2);
  u16* Wc    = (u16*)takeb((size_t)3072 * 512 * 2);
  u16* Wd    = (u16*)takeb((size_t)3072 * 192 * 2);
  u16* W1h   = (u16*)takeb((size_t)3072 * 1024 * 2);
  u16* W2i   = (u16*)takeb((size_t)3072 * 1024 * 2);
  u16* W2h   = (u16*)takeb((size_t)3072 * 1024 * 2);
  u16* WBy   = (u16*)takeb((size_t)256 * 1024 * 2);
  u16* P     = (u16*)takeb((size_t)32768 * 192 * 2);   // prev matrix, all t
  // base ~116 MiB. Rolling gi1 buffer (12.6 MiB) for the fast path.
  u16* g1A = nullptr;
  if (ws_size >= off + (size_t)2048 * 3072 * 2 + 256) g1A = (u16*)takeb((size_t)2048 * 3072 * 2);
  (void)in_sizes; (void)n_in; (void)out_size;

  const int BIG = 1 << 30;

  // --- prep + init ---
  mega_prep<<<57600, 256, 0, stream>>>(c, fiw, g1whh, g2wih, g2whh, g1wih, fcow, target,
                                       cbf, Wfi, W1h, W2i, W2h, Wc, Wd, WBy, P);
  gemm_A<<<dim3(40, 16), 512, 0, stream>>>(cbf, Wfi, Wc, fib, g1bih,
                                           h1f, h2f, h1b, h2b, gic);

  if (g1A != nullptr) {
    // gh1 | gh2 | gi1(0) init
    gemm_B<<<dim3(72, 16), 512, 0, stream>>>(h1b, h2b, P, W1h, W2h, Wd,
                                             g1bhh, g2bhh, gic, gh1, gh2, g1A);
    // C(0): combine1(0)
    gru2<<<2048, 256, 0, stream>>>(g1A, gh1, h1f, h1b, nullptr, nullptr, nullptr, nullptr, 1, 0);
    // G(0): gi2(0), gh1'(0->1), gi1(1)
    gemm_fused<<<dim3(72, 16), 512, 0, stream>>>(h1b, h2b, P + (size_t)1 * 2048 * 192,
                                                 W2i, W1h, W2h, WBy, Wd,
                                                 g2bih, g1bhh, g2bhh, fcob, gic,
                                                 gib, gh1, gh2, out, g1A,
                                                 24, 48, 48, 48, 0);
    for (int t = 1; t <= 14; ++t) {
      // C(t): combine1(t) [g1A, gh1] + combine2(t-1) [gib, gh2]
      gru2<<<2048, 256, 0, stream>>>(g1A, gh1, h1f, h1b, gib, gh2, h2f, h2b, 1, 1);
      // G(t): gi2(t), gh1'(t+1), gh2'(t), y(t-1), gi1(t+1)
      gemm_fused<<<dim3(98, 16), 512, 0, stream>>>(h1b, h2b, P + (size_t)(t + 1) * 2048 * 192,
                                                   W2i, W1h, W2h, WBy, Wd,
                                                   g2bih, g1bhh, g2bhh, fcob, gic,
                                                   gib, gh1, gh2, out, g1A,
                                                   24, 48, 72, 74, t - 1);
    }
    // C(15): combine1(15) + combine2(14)
    gru2<<<2048, 256, 0, stream>>>(g1A, gh1, h1f, h1b, gib, gh2, h2f, h2b, 1, 1);
    // G(15): gi2(15) + gh2(15) + y(14)  [r13 fix: gh2(15) restored]
    gemm_fused<<<dim3(50, 16), 512, 0, stream>>>(h1b, h2b, P,
                                                 W2i, W1h, W2h, WBy, Wd,
                                                 g2bih, g1bhh, g2bhh, fcob, gic,
                                                 gib, gh1, gh2, out, g1A,
                                                 24, 24, 48, 50, 14);
    // C(16): combine2(15)
    gru2<<<2048, 256, 0, stream>>>(nullptr, nullptr, nullptr, nullptr,
                                   gib, gh2, h2f, h2b, 0, 1);
    // G(16): y(15) only
    gemm_fused<<<dim3(2, 16), 512, 0, stream>>>(h1b, h2b, P,
                                                W2i, W1h, W2h, WBy, Wd,
                                                g2bih, g1bhh, g2bhh, fcob, gic,
                                                gib, gh1, gh2, out, g1A,
                                                0, 0, 0, 2, 15);
  } else {
    // fallback (tiny ws): per-step sequence; gh1/gh2 init via gemm_B grid 48
    gemm_B<<<dim3(48, 16), 512, 0, stream>>>(h1b, h2b, P, W1h, W2h, Wd,
                                             g1bhh, g2bhh, gic, gh1, gh2, nullptr);
    for (int t = 0; t < 16; ++t) {
      gemm_bt<<<dim3(24, 16), 512, 0, stream>>>(P + (size_t)t * 2048 * 192, 192, Wd, nullptr, 192, BIG,
                                                3072, 192, 2, 0, 0, nullptr, nullptr,
                                                gib, nullptr, gic, nullptr, nullptr);
      gru2<<<2048, 256, 0, stream>>>(gib, gh1, h1f, h1b, nullptr, nullptr, nullptr, nullptr, 1, 0);
      gemm_bt<<<dim3(48, 16), 512, 0, stream>>>(h1b, 1024, W2i, W1h, 1024, 3072,
                                                6144, 1024, 3, 0, 0, g2bih, g1bhh,
                                                gib, gh1, nullptr, nullptr, nullptr);
      gru2<<<2048, 256, 0, stream>>>(gib, gh2, h2f, h2b, nullptr, nullptr, nullptr, nullptr, 1, 0);
      gemm_bt<<<dim3(26, 16), 512, 0, stream>>>(h2b, 1024, W2h, WBy, 1024, 3072,
                                                3328, 1024, 4, t, 0, g2bhh, fcob,
                                                gh2, nullptr, nullptr, out, nullptr);
    }
  }
}